// Round 1
// baseline (783.918 us; speedup 1.0000x reference)
//
#include <hip/hip_runtime.h>

#define NBINS 31
#define NB1 2048    // k_reduce grid
#define NB2 2048    // k_hist grid: 16KB LDS -> 8 blocks/CU -> 2048 co-resident
#define HPITCH 128  // words per hist row; within a wave slot=tid&127 -> banks tid%32 -> 2-way (free)

struct Partial {                       // 32 B, one per k_reduce block
    unsigned int mnk, mxk, nz, pad;
    double s, ss;
};
// ws layout:
//   [0, NB1*32)        Partial part[NB1]      (64 KB)
//   [OFF_G, +128)      unsigned ghist[NBINS]  (device-atomic final histogram)
//   [OFF_CTR, +4)      unsigned ctr           (last-block-done counter)
#define OFF_G (NB1 * 32)
#define OFF_CTR (OFF_G + 128)

__device__ __forceinline__ unsigned int fkey(float f) {
    unsigned int u = __float_as_uint(f);
    return (u & 0x80000000u) ? ~u : (u | 0x80000000u);
}
__device__ __forceinline__ float funkey(unsigned int k) {
    return (k & 0x80000000u) ? __uint_as_float(k & 0x7FFFFFFFu)
                             : __uint_as_float(~k);
}
// Must match edges written to out exactly: mul then add, no FMA contraction.
__device__ __forceinline__ float edge_at(float mn, float step, float fi) {
    return __fadd_rn(mn, __fmul_rn(fi, step));
}

__device__ __forceinline__ void acc4(float4 v, float& mn, float& mx, float& s, float& ss,
                                     unsigned int& nz) {
    mn = fminf(mn, fminf(fminf(v.x, v.y), fminf(v.z, v.w)));
    mx = fmaxf(mx, fmaxf(fmaxf(v.x, v.y), fmaxf(v.z, v.w)));
    s  += (v.x + v.y) + (v.z + v.w);
    ss += (v.x * v.x + v.y * v.y) + (v.z * v.z + v.w * v.w);
    nz += (v.x != 0.f) + (v.y != 0.f) + (v.z != 0.f) + (v.w != 0.f);
}

__global__ void __launch_bounds__(256) k_reduce(const float* __restrict__ x, long long n,
                                                Partial* __restrict__ part,
                                                unsigned int* __restrict__ ghist,
                                                unsigned int* __restrict__ ctr) {
    // init atomic targets for the NEXT dispatch (ws is poisoned each iteration);
    // dispatch-boundary ordering guarantees visibility before k_hist runs.
    if (blockIdx.x == 0) {
        if (threadIdx.x < NBINS) ghist[threadIdx.x] = 0u;
        if (threadIdx.x == 32) *ctr = 0u;
    }

    long long n4 = n >> 2;
    const float4* __restrict__ x4 = (const float4*)x;
    float mn = INFINITY, mx = -INFINITY, s = 0.f, ss = 0.f;
    unsigned int nz = 0u;

    long long stride = (long long)gridDim.x * blockDim.x;
    long long i = (long long)blockIdx.x * blockDim.x + threadIdx.x;
    for (; i + 3 * stride < n4; i += 4 * stride) {       // 4 independent loads in flight
        float4 a = x4[i], b = x4[i + stride], c = x4[i + 2 * stride], d = x4[i + 3 * stride];
        acc4(a, mn, mx, s, ss, nz);
        acc4(b, mn, mx, s, ss, nz);
        acc4(c, mn, mx, s, ss, nz);
        acc4(d, mn, mx, s, ss, nz);
    }
    for (; i < n4; i += stride) acc4(x4[i], mn, mx, s, ss, nz);
    if (blockIdx.x == 0 && threadIdx.x < (int)(n & 3)) {  // scalar tail
        float v = x[(n4 << 2) + threadIdx.x];
        mn = fminf(mn, v); mx = fmaxf(mx, v);
        s += v; ss += v * v; nz += (v != 0.f);
    }

    // wave(64) reduce
    double sd = (double)s, ssd = (double)ss;
    #pragma unroll
    for (int off = 32; off > 0; off >>= 1) {
        mn = fminf(mn, __shfl_down(mn, off));
        mx = fmaxf(mx, __shfl_down(mx, off));
        sd  += __shfl_down(sd, off);
        ssd += __shfl_down(ssd, off);
        nz  += __shfl_down(nz, off);
    }
    __shared__ float lmn[4], lmx[4];
    __shared__ double lsum[4], lss[4];
    __shared__ unsigned int lnz[4];
    int w = threadIdx.x >> 6;
    if ((threadIdx.x & 63) == 0) { lmn[w] = mn; lmx[w] = mx; lsum[w] = sd; lss[w] = ssd; lnz[w] = nz; }
    __syncthreads();
    if (threadIdx.x == 0) {
        Partial p;
        p.mnk = fkey(fminf(fminf(lmn[0], lmn[1]), fminf(lmn[2], lmn[3])));
        p.mxk = fkey(fmaxf(fmaxf(lmx[0], lmx[1]), fmaxf(lmx[2], lmx[3])));
        p.nz  = lnz[0] + lnz[1] + lnz[2] + lnz[3];
        p.pad = 0;
        p.s  = lsum[0] + lsum[1] + lsum[2] + lsum[3];
        p.ss = lss[0] + lss[1] + lss[2] + lss[3];
        part[blockIdx.x] = p;
    }
}

// Branchless exact bin. Edges are recomputed in VALU (bit-identical to the emitted edge
// table) instead of LDS reads: cuts DS ops from 3/elem to 1/elem.
// (float)(b+1) == bf+1.0f exactly for b in [0,30]. E[31]=mx special case is equivalent
// after the final clamp (proof: whether v>=edge_at(31) or v>=mx bumps 30->31, both clamp to 30).
__device__ __forceinline__ void bump(float v, float mn, float step, float inv,
                                     unsigned int* __restrict__ hist, int slot) {
    int b = (int)((v - mn) * inv);
    b = b > 30 ? 30 : b;                 // (v-mn)>=0 so b>=0 already
    float bf = (float)b;
    float lo = edge_at(mn, step, bf);
    float hi = edge_at(mn, step, bf + 1.0f);
    b += (v >= hi);
    b -= (v < lo);
    b = b > 30 ? 30 : b;
    atomicAdd(&hist[(b << 7) + slot], 1u);
}

__global__ void __launch_bounds__(256) k_hist(const float* __restrict__ x, long long n,
                                              const Partial* __restrict__ part,
                                              unsigned int* __restrict__ ghist,
                                              unsigned int* __restrict__ ctr,
                                              float* __restrict__ out) {
    __shared__ unsigned int hist[NBINS * HPITCH];
    __shared__ unsigned int lmnk[4], lmxk[4];
    __shared__ int islast;
    int tid = threadIdx.x;
    for (int j = tid; j < NBINS * HPITCH; j += 256) hist[j] = 0u;

    // ---- preamble: global min/max from partials (replaces k_mid on the critical path) ----
    unsigned int mnk = 0xFFFFFFFFu, mxk = 0u;
    for (int ii = tid; ii < NB1; ii += 256) {
        uint2 p = *(const uint2*)&part[ii].mnk;      // mnk, mxk only (8B of 32B line)
        mnk = min(mnk, p.x); mxk = max(mxk, p.y);
    }
    #pragma unroll
    for (int off = 32; off > 0; off >>= 1) {
        mnk = min(mnk, __shfl_down(mnk, off));
        mxk = max(mxk, __shfl_down(mxk, off));
    }
    int w = tid >> 6;
    if ((tid & 63) == 0) { lmnk[w] = mnk; lmxk[w] = mxk; }
    __syncthreads();                                  // also covers hist[] zeroing
    float mn = funkey(min(min(lmnk[0], lmnk[1]), min(lmnk[2], lmnk[3])));
    float mx = funkey(max(max(lmxk[0], lmxk[1]), max(lmxk[2], lmxk[3])));
    float step = (mx - mn) / 31.0f;
    float inv  = 31.0f / (mx - mn);

    // ---- block 0: finalize scalars + edges early, overlapped with others' histogramming ----
    if (blockIdx.x == 0) {
        unsigned long long nz = 0ull; double s = 0.0, ss = 0.0;
        for (int ii = tid; ii < NB1; ii += 256) {
            Partial p = part[ii];
            nz += p.nz; s += p.s; ss += p.ss;
        }
        #pragma unroll
        for (int off = 32; off > 0; off >>= 1) {
            nz += __shfl_down(nz, off);
            s  += __shfl_down(s, off);
            ss += __shfl_down(ss, off);
        }
        __shared__ unsigned long long lnz[4];
        __shared__ double ls[4], lss2[4];
        if ((tid & 63) == 0) { lnz[w] = nz; ls[w] = s; lss2[w] = ss; }
        __syncthreads();
        if (tid == 0) {
            out[0] = mn;
            out[1] = mx;
            out[2] = (float)n;
            out[3] = (float)(lnz[0] + lnz[1] + lnz[2] + lnz[3]);
            out[4] = (float)(ls[0] + ls[1] + ls[2] + ls[3]);
            out[5] = (float)(lss2[0] + lss2[1] + lss2[2] + lss2[3]);
        }
        if (tid < NBINS + 1)
            out[6 + NBINS + tid] = (tid == NBINS) ? mx : edge_at(mn, step, (float)tid);
    }

    // ---- histogram main loop ----
    int slot = tid & (HPITCH - 1);
    long long n4 = n >> 2;
    const float4* __restrict__ x4 = (const float4*)x;
    long long stride = (long long)gridDim.x * blockDim.x;
    long long i = (long long)blockIdx.x * blockDim.x + tid;
    for (; i + stride < n4; i += 2 * stride) {
        float4 a = x4[i], b = x4[i + stride];
        bump(a.x, mn, step, inv, hist, slot); bump(a.y, mn, step, inv, hist, slot);
        bump(a.z, mn, step, inv, hist, slot); bump(a.w, mn, step, inv, hist, slot);
        bump(b.x, mn, step, inv, hist, slot); bump(b.y, mn, step, inv, hist, slot);
        bump(b.z, mn, step, inv, hist, slot); bump(b.w, mn, step, inv, hist, slot);
    }
    for (; i < n4; i += stride) {
        float4 a = x4[i];
        bump(a.x, mn, step, inv, hist, slot); bump(a.y, mn, step, inv, hist, slot);
        bump(a.z, mn, step, inv, hist, slot); bump(a.w, mn, step, inv, hist, slot);
    }
    if (blockIdx.x == 0 && tid < (int)(n & 3))
        bump(x[(n4 << 2) + tid], mn, step, inv, hist, slot);
    __syncthreads();

    // ---- block reduce -> device-scope atomic commit (replaces cpart + k_final) ----
    int lane = tid & 63;
    for (int b = w; b < NBINS; b += 4) {
        const unsigned int* row = &hist[b << 7];
        uint2 q = *(const uint2*)(row + (lane << 1));
        unsigned int sv = q.x + q.y;
        #pragma unroll
        for (int off = 32; off > 0; off >>= 1) sv += __shfl_down(sv, off);
        if (lane == 0) atomicAdd(&ghist[b], sv);
    }

    // ---- last-done block copies final counts (all traffic on coherent atomic path) ----
    __syncthreads();                                  // drains vmcnt -> our atomics complete
    if (tid == 0) {
        __threadfence();
        islast = (atomicAdd(ctr, 1u) == (unsigned int)(gridDim.x - 1));
    }
    __syncthreads();
    if (islast && tid < NBINS)
        out[6 + tid] = (float)atomicAdd(&ghist[tid], 0u);   // atomic read: device-coherent
}

extern "C" void kernel_launch(void* const* d_in, const int* in_sizes, int n_in,
                              void* d_out, int out_size, void* d_ws, size_t ws_size,
                              hipStream_t stream) {
    const float* x = (const float*)d_in[0];
    long long n = (long long)in_sizes[0];
    char* ws = (char*)d_ws;
    Partial* part = (Partial*)ws;
    unsigned int* ghist = (unsigned int*)(ws + OFF_G);
    unsigned int* ctr = (unsigned int*)(ws + OFF_CTR);
    float* out = (float*)d_out;

    k_reduce<<<dim3(NB1), dim3(256), 0, stream>>>(x, n, part, ghist, ctr);
    k_hist<<<dim3(NB2), dim3(256), 0, stream>>>(x, n, part, ghist, ctr, out);
}

// Round 2
// 463.771 us; speedup vs baseline: 1.6903x; 1.6903x over previous
//
#include <hip/hip_runtime.h>

#define NBINS 31
#define NB1 2048    // k_reduce grid
#define NB2 2048    // k_hist grid: 16KB LDS -> 8 blocks/CU -> 2048 co-resident
#define HPITCH 128  // words per hist row; within a wave slot=tid&127 -> banks tid%32 -> 2-way (free)
#define NREP 8      // ghist replicas: contention per address = NB2/NREP = 256
#define GSTRIDE 32  // words between ghist accumulators -> one 128B line each (no line sharing)

struct Partial {                       // 32 B, one per k_reduce block
    unsigned int mnk, mxk, nz, pad;
    double s, ss;
};
// ws layout:
//   [0, NB1*32)          Partial part[NB1]                      (64 KB)
//   [OFF_G, +31744)      unsigned ghist[NBINS*NREP][GSTRIDE]    (word [i][0] used; own line each)
//   [OFF_CTR, +4)        unsigned ctr                           (last-block-done counter)
#define OFF_G (NB1 * 32)
#define OFF_CTR (OFF_G + NBINS * NREP * GSTRIDE * 4)

__device__ __forceinline__ unsigned int fkey(float f) {
    unsigned int u = __float_as_uint(f);
    return (u & 0x80000000u) ? ~u : (u | 0x80000000u);
}
__device__ __forceinline__ float funkey(unsigned int k) {
    return (k & 0x80000000u) ? __uint_as_float(k & 0x7FFFFFFFu)
                             : __uint_as_float(~k);
}
// Must match edges written to out exactly: mul then add, no FMA contraction.
__device__ __forceinline__ float edge_at(float mn, float step, float fi) {
    return __fadd_rn(mn, __fmul_rn(fi, step));
}

__device__ __forceinline__ void acc4(float4 v, float& mn, float& mx, float& s, float& ss,
                                     unsigned int& nz) {
    mn = fminf(mn, fminf(fminf(v.x, v.y), fminf(v.z, v.w)));
    mx = fmaxf(mx, fmaxf(fmaxf(v.x, v.y), fmaxf(v.z, v.w)));
    s  += (v.x + v.y) + (v.z + v.w);
    ss += (v.x * v.x + v.y * v.y) + (v.z * v.z + v.w * v.w);
    nz += (v.x != 0.f) + (v.y != 0.f) + (v.z != 0.f) + (v.w != 0.f);
}

__global__ void __launch_bounds__(256) k_reduce(const float* __restrict__ x, long long n,
                                                Partial* __restrict__ part,
                                                unsigned int* __restrict__ ghist,
                                                unsigned int* __restrict__ ctr) {
    // init atomic targets for the NEXT dispatch (ws is poisoned each iteration);
    // dispatch-boundary release/acquire guarantees visibility before k_hist runs.
    if (blockIdx.x == 0) {
        if (threadIdx.x < NBINS * NREP) ghist[threadIdx.x * GSTRIDE] = 0u;
        if (threadIdx.x == 255) *ctr = 0u;
    }

    long long n4 = n >> 2;
    const float4* __restrict__ x4 = (const float4*)x;
    float mn = INFINITY, mx = -INFINITY, s = 0.f, ss = 0.f;
    unsigned int nz = 0u;

    long long stride = (long long)gridDim.x * blockDim.x;
    long long i = (long long)blockIdx.x * blockDim.x + threadIdx.x;
    for (; i + 3 * stride < n4; i += 4 * stride) {       // 4 independent loads in flight
        float4 a = x4[i], b = x4[i + stride], c = x4[i + 2 * stride], d = x4[i + 3 * stride];
        acc4(a, mn, mx, s, ss, nz);
        acc4(b, mn, mx, s, ss, nz);
        acc4(c, mn, mx, s, ss, nz);
        acc4(d, mn, mx, s, ss, nz);
    }
    for (; i < n4; i += stride) acc4(x4[i], mn, mx, s, ss, nz);
    if (blockIdx.x == 0 && threadIdx.x < (int)(n & 3)) {  // scalar tail
        float v = x[(n4 << 2) + threadIdx.x];
        mn = fminf(mn, v); mx = fmaxf(mx, v);
        s += v; ss += v * v; nz += (v != 0.f);
    }

    // wave(64) reduce
    double sd = (double)s, ssd = (double)ss;
    #pragma unroll
    for (int off = 32; off > 0; off >>= 1) {
        mn = fminf(mn, __shfl_down(mn, off));
        mx = fmaxf(mx, __shfl_down(mx, off));
        sd  += __shfl_down(sd, off);
        ssd += __shfl_down(ssd, off);
        nz  += __shfl_down(nz, off);
    }
    __shared__ float lmn[4], lmx[4];
    __shared__ double lsum[4], lss[4];
    __shared__ unsigned int lnz[4];
    int w = threadIdx.x >> 6;
    if ((threadIdx.x & 63) == 0) { lmn[w] = mn; lmx[w] = mx; lsum[w] = sd; lss[w] = ssd; lnz[w] = nz; }
    __syncthreads();
    if (threadIdx.x == 0) {
        Partial p;
        p.mnk = fkey(fminf(fminf(lmn[0], lmn[1]), fminf(lmn[2], lmn[3])));
        p.mxk = fkey(fmaxf(fmaxf(lmx[0], lmx[1]), fmaxf(lmx[2], lmx[3])));
        p.nz  = lnz[0] + lnz[1] + lnz[2] + lnz[3];
        p.pad = 0;
        p.s  = lsum[0] + lsum[1] + lsum[2] + lsum[3];
        p.ss = lss[0] + lss[1] + lss[2] + lss[3];
        part[blockIdx.x] = p;
    }
}

// Branchless exact bin. Edges recomputed in VALU (bit-identical to the emitted edge table):
// 1 DS op/elem instead of 3. (float)(b+1) == bf+1.0f exactly for b in [0,30]. E[31]=mx
// special case equivalent after the final clamp.
__device__ __forceinline__ void bump(float v, float mn, float step, float inv,
                                     unsigned int* __restrict__ hist, int slot) {
    int b = (int)((v - mn) * inv);
    b = b > 30 ? 30 : b;                 // (v-mn)>=0 so b>=0 already
    float bf = (float)b;
    float lo = edge_at(mn, step, bf);
    float hi = edge_at(mn, step, bf + 1.0f);
    b += (v >= hi);
    b -= (v < lo);
    b = b > 30 ? 30 : b;
    atomicAdd(&hist[(b << 7) + slot], 1u);
}

__global__ void __launch_bounds__(256) k_hist(const float* __restrict__ x, long long n,
                                              const Partial* __restrict__ part,
                                              unsigned int* __restrict__ ghist,
                                              unsigned int* __restrict__ ctr,
                                              float* __restrict__ out) {
    __shared__ unsigned int hist[NBINS * HPITCH];
    __shared__ unsigned int lmnk[4], lmxk[4];
    __shared__ int islast;
    int tid = threadIdx.x;
    for (int j = tid; j < NBINS * HPITCH; j += 256) hist[j] = 0u;

    // ---- preamble: global min/max from partials (k_mid fused off the critical path) ----
    unsigned int mnk = 0xFFFFFFFFu, mxk = 0u;
    for (int ii = tid; ii < NB1; ii += 256) {
        uint2 p = *(const uint2*)&part[ii].mnk;      // mnk, mxk only (8B of 32B line)
        mnk = min(mnk, p.x); mxk = max(mxk, p.y);
    }
    #pragma unroll
    for (int off = 32; off > 0; off >>= 1) {
        mnk = min(mnk, __shfl_down(mnk, off));
        mxk = max(mxk, __shfl_down(mxk, off));
    }
    int w = tid >> 6;
    if ((tid & 63) == 0) { lmnk[w] = mnk; lmxk[w] = mxk; }
    __syncthreads();                                  // also covers hist[] zeroing
    float mn = funkey(min(min(lmnk[0], lmnk[1]), min(lmnk[2], lmnk[3])));
    float mx = funkey(max(max(lmxk[0], lmxk[1]), max(lmxk[2], lmxk[3])));
    float step = (mx - mn) / 31.0f;
    float inv  = 31.0f / (mx - mn);

    // ---- block 0: finalize scalars + edges early, overlapped with others' histogramming ----
    if (blockIdx.x == 0) {
        unsigned long long nz = 0ull; double s = 0.0, ss = 0.0;
        for (int ii = tid; ii < NB1; ii += 256) {
            Partial p = part[ii];
            nz += p.nz; s += p.s; ss += p.ss;
        }
        #pragma unroll
        for (int off = 32; off > 0; off >>= 1) {
            nz += __shfl_down(nz, off);
            s  += __shfl_down(s, off);
            ss += __shfl_down(ss, off);
        }
        __shared__ unsigned long long lnz[4];
        __shared__ double ls[4], lss2[4];
        if ((tid & 63) == 0) { lnz[w] = nz; ls[w] = s; lss2[w] = ss; }
        __syncthreads();
        if (tid == 0) {
            out[0] = mn;
            out[1] = mx;
            out[2] = (float)n;
            out[3] = (float)(lnz[0] + lnz[1] + lnz[2] + lnz[3]);
            out[4] = (float)(ls[0] + ls[1] + ls[2] + ls[3]);
            out[5] = (float)(lss2[0] + lss2[1] + lss2[2] + lss2[3]);
        }
        if (tid < NBINS + 1)
            out[6 + NBINS + tid] = (tid == NBINS) ? mx : edge_at(mn, step, (float)tid);
    }

    // ---- histogram main loop ----
    int slot = tid & (HPITCH - 1);
    long long n4 = n >> 2;
    const float4* __restrict__ x4 = (const float4*)x;
    long long stride = (long long)gridDim.x * blockDim.x;
    long long i = (long long)blockIdx.x * blockDim.x + tid;
    for (; i + stride < n4; i += 2 * stride) {
        float4 a = x4[i], b = x4[i + stride];
        bump(a.x, mn, step, inv, hist, slot); bump(a.y, mn, step, inv, hist, slot);
        bump(a.z, mn, step, inv, hist, slot); bump(a.w, mn, step, inv, hist, slot);
        bump(b.x, mn, step, inv, hist, slot); bump(b.y, mn, step, inv, hist, slot);
        bump(b.z, mn, step, inv, hist, slot); bump(b.w, mn, step, inv, hist, slot);
    }
    for (; i < n4; i += stride) {
        float4 a = x4[i];
        bump(a.x, mn, step, inv, hist, slot); bump(a.y, mn, step, inv, hist, slot);
        bump(a.z, mn, step, inv, hist, slot); bump(a.w, mn, step, inv, hist, slot);
    }
    if (blockIdx.x == 0 && tid < (int)(n & 3))
        bump(x[(n4 << 2) + tid], mn, step, inv, hist, slot);
    __syncthreads();

    // ---- block reduce -> replicated, line-padded atomic commit ----
    // Round-1 lesson: 63.5K far atomics into ONE cache line serialized at ~7ns each (+380us).
    // Now: (bin, blockIdx&7) -> own 128B line; contention/address <=256, 248 chains in parallel.
    int lane = tid & 63;
    int rep = blockIdx.x & (NREP - 1);
    for (int b = w; b < NBINS; b += 4) {
        const unsigned int* row = &hist[b << 7];
        uint2 q = *(const uint2*)(row + (lane << 1));
        unsigned int sv = q.x + q.y;
        #pragma unroll
        for (int off = 32; off > 0; off >>= 1) sv += __shfl_down(sv, off);
        if (lane == 0 && sv) atomicAdd(&ghist[(b * NREP + rep) * GSTRIDE], sv);
    }

    // ---- last-done block copies final counts (all traffic on coherent atomic path) ----
    __syncthreads();                                  // waitcnt before barrier drains our atomics
    if (tid == 0) {
        __threadfence();
        islast = (atomicAdd(ctr, 1u) == (unsigned int)(gridDim.x - 1));
    }
    __syncthreads();
    if (islast && tid < NBINS) {
        unsigned int tot = 0;
        #pragma unroll
        for (int r = 0; r < NREP; ++r)
            tot += atomicAdd(&ghist[(tid * NREP + r) * GSTRIDE], 0u);  // coherent atomic read
        out[6 + tid] = (float)tot;
    }
}

extern "C" void kernel_launch(void* const* d_in, const int* in_sizes, int n_in,
                              void* d_out, int out_size, void* d_ws, size_t ws_size,
                              hipStream_t stream) {
    const float* x = (const float*)d_in[0];
    long long n = (long long)in_sizes[0];
    char* ws = (char*)d_ws;
    Partial* part = (Partial*)ws;
    unsigned int* ghist = (unsigned int*)(ws + OFF_G);
    unsigned int* ctr = (unsigned int*)(ws + OFF_CTR);
    float* out = (float*)d_out;

    k_reduce<<<dim3(NB1), dim3(256), 0, stream>>>(x, n, part, ghist, ctr);
    k_hist<<<dim3(NB2), dim3(256), 0, stream>>>(x, n, part, ghist, ctr, out);
}

// Round 3
// 408.313 us; speedup vs baseline: 1.9199x; 1.1358x over previous
//
#include <hip/hip_runtime.h>

#define NBINS 31
#define NB1 2048    // k_reduce grid
#define NB2 2048    // k_hist grid: 16KB LDS -> 8 blocks/CU -> 2048 co-resident
#define HPITCH 128  // words per hist row; within a wave slot=tid&127 -> banks tid%32 -> 2-way (free)
#define NREP 8      // ghist replicas: contention per address = NB2/NREP = 256
#define GSTRIDE 32  // words between ghist accumulators -> one 128B line each (no line sharing)

struct Partial {                       // 32 B, one per k_reduce block
    unsigned int mnk, mxk, nz, pad;
    double s, ss;
};
// ws layout:
//   [0, NB1*32)          Partial part[NB1]                      (64 KB)
//   [OFF_G, +31744)      unsigned ghist[NBINS*NREP][GSTRIDE]    (word [i][0] used; own line each)
#define OFF_G (NB1 * 32)

__device__ __forceinline__ unsigned int fkey(float f) {
    unsigned int u = __float_as_uint(f);
    return (u & 0x80000000u) ? ~u : (u | 0x80000000u);
}
__device__ __forceinline__ float funkey(unsigned int k) {
    return (k & 0x80000000u) ? __uint_as_float(k & 0x7FFFFFFFu)
                             : __uint_as_float(~k);
}
// Must match edges written to out exactly: mul then add, no FMA contraction.
__device__ __forceinline__ float edge_at(float mn, float step, float fi) {
    return __fadd_rn(mn, __fmul_rn(fi, step));
}

__device__ __forceinline__ void acc4(float4 v, float& mn, float& mx, float& s, float& ss,
                                     unsigned int& nz) {
    mn = fminf(mn, fminf(fminf(v.x, v.y), fminf(v.z, v.w)));
    mx = fmaxf(mx, fmaxf(fmaxf(v.x, v.y), fmaxf(v.z, v.w)));
    s  += (v.x + v.y) + (v.z + v.w);
    ss += (v.x * v.x + v.y * v.y) + (v.z * v.z + v.w * v.w);
    nz += (v.x != 0.f) + (v.y != 0.f) + (v.z != 0.f) + (v.w != 0.f);
}

__global__ void __launch_bounds__(256) k_reduce(const float* __restrict__ x, long long n,
                                                Partial* __restrict__ part,
                                                unsigned int* __restrict__ ghist) {
    // zero the atomic targets for the NEXT dispatch (ws is re-poisoned every iteration);
    // dispatch-boundary release/acquire makes this visible before k_hist runs.
    if (blockIdx.x == 0 && threadIdx.x < NBINS * NREP) ghist[threadIdx.x * GSTRIDE] = 0u;

    long long n4 = n >> 2;
    const float4* __restrict__ x4 = (const float4*)x;
    float mn = INFINITY, mx = -INFINITY, s = 0.f, ss = 0.f;
    unsigned int nz = 0u;

    // FORWARD traversal (k_hist goes backward: boustrophedon maximizes L3 reuse).
    long long stride = (long long)gridDim.x * blockDim.x;
    long long i = (long long)blockIdx.x * blockDim.x + threadIdx.x;
    for (; i + 3 * stride < n4; i += 4 * stride) {       // 4 independent loads in flight
        float4 a = x4[i], b = x4[i + stride], c = x4[i + 2 * stride], d = x4[i + 3 * stride];
        acc4(a, mn, mx, s, ss, nz);
        acc4(b, mn, mx, s, ss, nz);
        acc4(c, mn, mx, s, ss, nz);
        acc4(d, mn, mx, s, ss, nz);
    }
    for (; i < n4; i += stride) acc4(x4[i], mn, mx, s, ss, nz);
    if (blockIdx.x == 0 && threadIdx.x < (int)(n & 3)) {  // scalar tail
        float v = x[(n4 << 2) + threadIdx.x];
        mn = fminf(mn, v); mx = fmaxf(mx, v);
        s += v; ss += v * v; nz += (v != 0.f);
    }

    // wave(64) reduce
    double sd = (double)s, ssd = (double)ss;
    #pragma unroll
    for (int off = 32; off > 0; off >>= 1) {
        mn = fminf(mn, __shfl_down(mn, off));
        mx = fmaxf(mx, __shfl_down(mx, off));
        sd  += __shfl_down(sd, off);
        ssd += __shfl_down(ssd, off);
        nz  += __shfl_down(nz, off);
    }
    __shared__ float lmn[4], lmx[4];
    __shared__ double lsum[4], lss[4];
    __shared__ unsigned int lnz[4];
    int w = threadIdx.x >> 6;
    if ((threadIdx.x & 63) == 0) { lmn[w] = mn; lmx[w] = mx; lsum[w] = sd; lss[w] = ssd; lnz[w] = nz; }
    __syncthreads();
    if (threadIdx.x == 0) {
        Partial p;
        p.mnk = fkey(fminf(fminf(lmn[0], lmn[1]), fminf(lmn[2], lmn[3])));
        p.mxk = fkey(fmaxf(fmaxf(lmx[0], lmx[1]), fmaxf(lmx[2], lmx[3])));
        p.nz  = lnz[0] + lnz[1] + lnz[2] + lnz[3];
        p.pad = 0;
        p.s  = lsum[0] + lsum[1] + lsum[2] + lsum[3];
        p.ss = lss[0] + lss[1] + lss[2] + lss[3];
        part[blockIdx.x] = p;
    }
}

// Branchless exact bin. Edges recomputed in VALU (bit-identical to the emitted edge table):
// 1 DS op/elem instead of 3. (float)(b+1) == bf+1.0f exactly for b in [0,30]. E[31]=mx
// special case equivalent after the final clamp.
__device__ __forceinline__ void bump(float v, float mn, float step, float inv,
                                     unsigned int* __restrict__ hist, int slot) {
    int b = (int)((v - mn) * inv);
    b = b > 30 ? 30 : b;                 // (v-mn)>=0 so b>=0 already
    float bf = (float)b;
    float lo = edge_at(mn, step, bf);
    float hi = edge_at(mn, step, bf + 1.0f);
    b += (v >= hi);
    b -= (v < lo);
    b = b > 30 ? 30 : b;
    atomicAdd(&hist[(b << 7) + slot], 1u);
}

__global__ void __launch_bounds__(256) k_hist(const float* __restrict__ x, long long n,
                                              const Partial* __restrict__ part,
                                              unsigned int* __restrict__ ghist,
                                              float* __restrict__ out) {
    __shared__ unsigned int hist[NBINS * HPITCH];
    __shared__ unsigned int lmnk[4], lmxk[4];
    int tid = threadIdx.x;
    for (int j = tid; j < NBINS * HPITCH; j += 256) hist[j] = 0u;

    // ---- preamble: global min/max from partials (k_mid fused off the critical path) ----
    unsigned int mnk = 0xFFFFFFFFu, mxk = 0u;
    for (int ii = tid; ii < NB1; ii += 256) {
        uint2 p = *(const uint2*)&part[ii].mnk;      // mnk, mxk only (8B of 32B line)
        mnk = min(mnk, p.x); mxk = max(mxk, p.y);
    }
    #pragma unroll
    for (int off = 32; off > 0; off >>= 1) {
        mnk = min(mnk, __shfl_down(mnk, off));
        mxk = max(mxk, __shfl_down(mxk, off));
    }
    int w = tid >> 6;
    if ((tid & 63) == 0) { lmnk[w] = mnk; lmxk[w] = mxk; }
    __syncthreads();                                  // also covers hist[] zeroing
    float mn = funkey(min(min(lmnk[0], lmnk[1]), min(lmnk[2], lmnk[3])));
    float mx = funkey(max(max(lmxk[0], lmxk[1]), max(lmxk[2], lmxk[3])));
    float step = (mx - mn) / 31.0f;
    float inv  = 31.0f / (mx - mn);

    // ---- block 0: finalize scalars + edges early, overlapped with others' histogramming ----
    if (blockIdx.x == 0) {
        unsigned long long nz = 0ull; double s = 0.0, ss = 0.0;
        for (int ii = tid; ii < NB1; ii += 256) {
            Partial p = part[ii];
            nz += p.nz; s += p.s; ss += p.ss;
        }
        #pragma unroll
        for (int off = 32; off > 0; off >>= 1) {
            nz += __shfl_down(nz, off);
            s  += __shfl_down(s, off);
            ss += __shfl_down(ss, off);
        }
        __shared__ unsigned long long lnz[4];
        __shared__ double ls[4], lss2[4];
        if ((tid & 63) == 0) { lnz[w] = nz; ls[w] = s; lss2[w] = ss; }
        __syncthreads();
        if (tid == 0) {
            out[0] = mn;
            out[1] = mx;
            out[2] = (float)n;
            out[3] = (float)(lnz[0] + lnz[1] + lnz[2] + lnz[3]);
            out[4] = (float)(ls[0] + ls[1] + ls[2] + ls[3]);
            out[5] = (float)(lss2[0] + lss2[1] + lss2[2] + lss2[3]);
        }
        if (tid < NBINS + 1)
            out[6 + NBINS + tid] = (tid == NBINS) ? mx : edge_at(mn, step, (float)tid);
    }

    // ---- histogram main loop: REVERSE traversal ----
    // k_reduce streamed x forward, leaving the tail resident in the 256MB L3 (measured:
    // k_hist fetched only ~134MB of 256MB). Reading tail-first converts more of those
    // residents into hits before they get evicted.
    int slot = tid & (HPITCH - 1);
    long long n4 = n >> 2;
    const float4* __restrict__ x4 = (const float4*)x;
    long long stride = (long long)gridDim.x * blockDim.x;
    long long base = (long long)blockIdx.x * blockDim.x + tid;

    if (blockIdx.x == 0 && tid < (int)(n & 3))          // scalar tail (highest addresses) first
        bump(x[(n4 << 2) + tid], mn, step, inv, hist, slot);

    long long nsteps = (n4 - base + stride - 1) / (2 * stride);   // # of pair-iterations
    if (nsteps < 0) nsteps = 0;
    for (long long i = base + 2 * nsteps * stride; i < n4; i += stride) {  // odd remainder
        float4 a = x4[i];
        bump(a.x, mn, step, inv, hist, slot); bump(a.y, mn, step, inv, hist, slot);
        bump(a.z, mn, step, inv, hist, slot); bump(a.w, mn, step, inv, hist, slot);
    }
    for (long long k = nsteps - 1; k >= 0; --k) {       // descending pairs
        long long i = base + 2 * k * stride;
        float4 b = x4[i + stride], a = x4[i];
        bump(b.x, mn, step, inv, hist, slot); bump(b.y, mn, step, inv, hist, slot);
        bump(b.z, mn, step, inv, hist, slot); bump(b.w, mn, step, inv, hist, slot);
        bump(a.x, mn, step, inv, hist, slot); bump(a.y, mn, step, inv, hist, slot);
        bump(a.z, mn, step, inv, hist, slot); bump(a.w, mn, step, inv, hist, slot);
    }
    __syncthreads();

    // ---- block reduce -> replicated, line-padded atomic commit ----
    // (bin, blockIdx&7) -> own 128B line; contention/address <=256; no end-of-kernel
    // handshake (round-2 lesson: per-block threadfence + single-word ret-atomic chain
    // cost ~50us). k_final picks the replicas up next dispatch.
    int lane = tid & 63;
    int rep = blockIdx.x & (NREP - 1);
    for (int b = w; b < NBINS; b += 4) {
        const unsigned int* row = &hist[b << 7];
        uint2 q = *(const uint2*)(row + (lane << 1));
        unsigned int sv = q.x + q.y;
        #pragma unroll
        for (int off = 32; off > 0; off >>= 1) sv += __shfl_down(sv, off);
        if (lane == 0 && sv) atomicAdd(&ghist[(b * NREP + rep) * GSTRIDE], sv);
    }
}

__global__ void __launch_bounds__(64) k_final(const unsigned int* __restrict__ ghist,
                                              float* __restrict__ out) {
    int t = threadIdx.x;
    if (t < NBINS) {
        unsigned int tot = 0;
        #pragma unroll
        for (int r = 0; r < NREP; ++r)
            tot += ghist[(t * NREP + r) * GSTRIDE];    // dispatch boundary = acquire
        out[6 + t] = (float)tot;
    }
}

extern "C" void kernel_launch(void* const* d_in, const int* in_sizes, int n_in,
                              void* d_out, int out_size, void* d_ws, size_t ws_size,
                              hipStream_t stream) {
    const float* x = (const float*)d_in[0];
    long long n = (long long)in_sizes[0];
    char* ws = (char*)d_ws;
    Partial* part = (Partial*)ws;
    unsigned int* ghist = (unsigned int*)(ws + OFF_G);
    float* out = (float*)d_out;

    k_reduce<<<dim3(NB1), dim3(256), 0, stream>>>(x, n, part, ghist);
    k_hist<<<dim3(NB2), dim3(256), 0, stream>>>(x, n, part, ghist, out);
    k_final<<<dim3(1), dim3(64), 0, stream>>>(ghist, out);
}

// Round 4
// 406.153 us; speedup vs baseline: 1.9301x; 1.0053x over previous
//
#include <hip/hip_runtime.h>

#define NBINS 31
#define NB1 2048    // k_reduce grid
#define NB2 2048    // k_hist grid: 16KB LDS -> 8 blocks/CU -> 2048 co-resident
#define HPITCH 128  // words per hist row; within a wave slot=tid&127 -> banks tid%32 -> 2-way (free)
#define NREP 8      // ghist replicas: contention per address = NB2/NREP = 256
#define GSTRIDE 32  // words between ghist accumulators -> one 128B line each (no line sharing)

struct Partial {                       // 32 B, one per k_reduce block
    unsigned int mnk, mxk, nz, pad;
    double s, ss;
};
// ws layout:
//   [0, NB1*32)          Partial part[NB1]                      (64 KB)
//   [OFF_G, +31744)      unsigned ghist[NBINS*NREP][GSTRIDE]    (word [i][0] used; own line each)
//   [OFF_MM, +16K)       uint2 mm[NB1]                          (compact min/max keys)
#define OFF_G (NB1 * 32)
#define OFF_MM (OFF_G + NBINS * NREP * GSTRIDE * 4)

__device__ __forceinline__ unsigned int fkey(float f) {
    unsigned int u = __float_as_uint(f);
    return (u & 0x80000000u) ? ~u : (u | 0x80000000u);
}
__device__ __forceinline__ float funkey(unsigned int k) {
    return (k & 0x80000000u) ? __uint_as_float(k & 0x7FFFFFFFu)
                             : __uint_as_float(~k);
}
// Must match edges written to out exactly: mul then add, no FMA contraction.
__device__ __forceinline__ float edge_at(float mn, float step, float fi) {
    return __fadd_rn(mn, __fmul_rn(fi, step));
}

__device__ __forceinline__ void acc4(float4 v, float& mn, float& mx, float& s, float& ss,
                                     unsigned int& nz) {
    mn = fminf(mn, fminf(fminf(v.x, v.y), fminf(v.z, v.w)));
    mx = fmaxf(mx, fmaxf(fmaxf(v.x, v.y), fmaxf(v.z, v.w)));
    s  += (v.x + v.y) + (v.z + v.w);
    ss += (v.x * v.x + v.y * v.y) + (v.z * v.z + v.w * v.w);
    nz += (v.x != 0.f) + (v.y != 0.f) + (v.z != 0.f) + (v.w != 0.f);
}

__global__ void __launch_bounds__(256) k_reduce(const float* __restrict__ x, long long n,
                                                Partial* __restrict__ part,
                                                unsigned int* __restrict__ ghist,
                                                uint2* __restrict__ mm) {
    // zero the atomic targets for the NEXT dispatch (ws is re-poisoned every iteration);
    // dispatch-boundary release/acquire makes this visible before k_hist runs.
    if (blockIdx.x == 0 && threadIdx.x < NBINS * NREP) ghist[threadIdx.x * GSTRIDE] = 0u;

    long long n4 = n >> 2;
    const float4* __restrict__ x4 = (const float4*)x;
    float mn = INFINITY, mx = -INFINITY, s = 0.f, ss = 0.f;
    unsigned int nz = 0u;

    // FORWARD traversal (k_hist goes backward: reverse rescan of an LRU-ish L3 hits,
    // forward rescan of an exact-fit working set misses).
    long long stride = (long long)gridDim.x * blockDim.x;
    long long i = (long long)blockIdx.x * blockDim.x + threadIdx.x;
    for (; i + 3 * stride < n4; i += 4 * stride) {       // 4 independent loads in flight
        float4 a = x4[i], b = x4[i + stride], c = x4[i + 2 * stride], d = x4[i + 3 * stride];
        acc4(a, mn, mx, s, ss, nz);
        acc4(b, mn, mx, s, ss, nz);
        acc4(c, mn, mx, s, ss, nz);
        acc4(d, mn, mx, s, ss, nz);
    }
    for (; i < n4; i += stride) acc4(x4[i], mn, mx, s, ss, nz);
    if (blockIdx.x == 0 && threadIdx.x < (int)(n & 3)) {  // scalar tail
        float v = x[(n4 << 2) + threadIdx.x];
        mn = fminf(mn, v); mx = fmaxf(mx, v);
        s += v; ss += v * v; nz += (v != 0.f);
    }

    // wave(64) reduce
    double sd = (double)s, ssd = (double)ss;
    #pragma unroll
    for (int off = 32; off > 0; off >>= 1) {
        mn = fminf(mn, __shfl_down(mn, off));
        mx = fmaxf(mx, __shfl_down(mx, off));
        sd  += __shfl_down(sd, off);
        ssd += __shfl_down(ssd, off);
        nz  += __shfl_down(nz, off);
    }
    __shared__ float lmn[4], lmx[4];
    __shared__ double lsum[4], lss[4];
    __shared__ unsigned int lnz[4];
    int w = threadIdx.x >> 6;
    if ((threadIdx.x & 63) == 0) { lmn[w] = mn; lmx[w] = mx; lsum[w] = sd; lss[w] = ssd; lnz[w] = nz; }
    __syncthreads();
    if (threadIdx.x == 0) {
        Partial p;
        p.mnk = fkey(fminf(fminf(lmn[0], lmn[1]), fminf(lmn[2], lmn[3])));
        p.mxk = fkey(fmaxf(fmaxf(lmx[0], lmx[1]), fmaxf(lmx[2], lmx[3])));
        p.nz  = lnz[0] + lnz[1] + lnz[2] + lnz[3];
        p.pad = 0;
        p.s  = lsum[0] + lsum[1] + lsum[2] + lsum[3];
        p.ss = lss[0] + lss[1] + lss[2] + lss[3];
        part[blockIdx.x] = p;
        mm[blockIdx.x] = make_uint2(p.mnk, p.mxk);    // compact copy: dense preamble reads
    }
}

// Branchless exact bin. Edges recomputed in VALU (bit-identical to the emitted edge table):
// 1 DS op/elem instead of 3. (float)(b+1) == bf+1.0f exactly for b in [0,30]. E[31]=mx
// special case equivalent after the final clamp.
__device__ __forceinline__ void bump(float v, float mn, float step, float inv,
                                     unsigned int* __restrict__ hist, int slot) {
    int b = (int)((v - mn) * inv);
    b = b > 30 ? 30 : b;                 // (v-mn)>=0 so b>=0 already
    float bf = (float)b;
    float lo = edge_at(mn, step, bf);
    float hi = edge_at(mn, step, bf + 1.0f);
    b += (v >= hi);
    b -= (v < lo);
    b = b > 30 ? 30 : b;
    atomicAdd(&hist[(b << 7) + slot], 1u);
}
#define BUMP4(v) do { bump((v).x, mn, step, inv, hist, slot); bump((v).y, mn, step, inv, hist, slot); \
                      bump((v).z, mn, step, inv, hist, slot); bump((v).w, mn, step, inv, hist, slot); } while (0)

__global__ void __launch_bounds__(256) k_hist(const float* __restrict__ x, long long n,
                                              const Partial* __restrict__ part,
                                              unsigned int* __restrict__ ghist,
                                              const uint2* __restrict__ mm,
                                              float* __restrict__ out) {
    __shared__ unsigned int hist[NBINS * HPITCH];
    __shared__ unsigned int lmnk[4], lmxk[4];
    int tid = threadIdx.x;
    for (int j = tid; j < NBINS * HPITCH; j += 256) hist[j] = 0u;

    // ---- preamble: global min/max from compact key array (dense, L2-resident) ----
    unsigned int mnk = 0xFFFFFFFFu, mxk = 0u;
    for (int ii = tid; ii < NB1; ii += 256) {
        uint2 p = mm[ii];
        mnk = min(mnk, p.x); mxk = max(mxk, p.y);
    }
    #pragma unroll
    for (int off = 32; off > 0; off >>= 1) {
        mnk = min(mnk, __shfl_down(mnk, off));
        mxk = max(mxk, __shfl_down(mxk, off));
    }
    int w = tid >> 6;
    if ((tid & 63) == 0) { lmnk[w] = mnk; lmxk[w] = mxk; }
    __syncthreads();                                  // also covers hist[] zeroing
    float mn = funkey(min(min(lmnk[0], lmnk[1]), min(lmnk[2], lmnk[3])));
    float mx = funkey(max(max(lmxk[0], lmxk[1]), max(lmxk[2], lmxk[3])));
    float step = (mx - mn) / 31.0f;
    float inv  = 31.0f / (mx - mn);

    // ---- block 0: finalize scalars + edges early, overlapped with others' histogramming ----
    if (blockIdx.x == 0) {
        unsigned long long nz = 0ull; double s = 0.0, ss = 0.0;
        for (int ii = tid; ii < NB1; ii += 256) {
            Partial p = part[ii];
            nz += p.nz; s += p.s; ss += p.ss;
        }
        #pragma unroll
        for (int off = 32; off > 0; off >>= 1) {
            nz += __shfl_down(nz, off);
            s  += __shfl_down(s, off);
            ss += __shfl_down(ss, off);
        }
        __shared__ unsigned long long lnz[4];
        __shared__ double ls[4], lss2[4];
        if ((tid & 63) == 0) { lnz[w] = nz; ls[w] = s; lss2[w] = ss; }
        __syncthreads();
        if (tid == 0) {
            out[0] = mn;
            out[1] = mx;
            out[2] = (float)n;
            out[3] = (float)(lnz[0] + lnz[1] + lnz[2] + lnz[3]);
            out[4] = (float)(ls[0] + ls[1] + ls[2] + ls[3]);
            out[5] = (float)(lss2[0] + lss2[1] + lss2[2] + lss2[3]);
        }
        if (tid < NBINS + 1)
            out[6 + NBINS + tid] = (tid == NBINS) ? mx : edge_at(mn, step, (float)tid);
    }

    // ---- histogram main loop: REVERSE traversal, 4 loads in flight ----
    int slot = tid & (HPITCH - 1);
    long long n4 = n >> 2;
    const float4* __restrict__ x4 = (const float4*)x;
    long long stride = (long long)gridDim.x * blockDim.x;
    long long base = (long long)blockIdx.x * blockDim.x + tid;

    if (blockIdx.x == 0 && tid < (int)(n & 3))          // scalar tail (highest addresses) first
        bump(x[(n4 << 2) + tid], mn, step, inv, hist, slot);

    long long cnt = (base < n4) ? (n4 - base + stride - 1) / stride : 0;  // # iterations
    long long k = cnt - 1;
    for (; k >= 0 && (k & 3) != 3; --k) {               // peel until k%4==3 (highest addrs first)
        float4 a = x4[base + k * stride];
        BUMP4(a);
    }
    for (; k >= 3; k -= 4) {                            // 4-deep MLP, descending
        float4 d = x4[base + k * stride];
        float4 c = x4[base + (k - 1) * stride];
        float4 b = x4[base + (k - 2) * stride];
        float4 a = x4[base + (k - 3) * stride];
        BUMP4(d); BUMP4(c); BUMP4(b); BUMP4(a);
    }
    __syncthreads();

    // ---- block reduce -> replicated, line-padded atomic commit ----
    // (bin, blockIdx&7) -> own 128B line; contention/address <=256; no end-of-kernel
    // handshake (round-2 lesson: per-block threadfence + single-word ret-atomic chain
    // cost ~50us). k_final picks the replicas up next dispatch.
    int lane = tid & 63;
    int rep = blockIdx.x & (NREP - 1);
    for (int b = w; b < NBINS; b += 4) {
        const unsigned int* row = &hist[b << 7];
        uint2 q = *(const uint2*)(row + (lane << 1));
        unsigned int sv = q.x + q.y;
        #pragma unroll
        for (int off = 32; off > 0; off >>= 1) sv += __shfl_down(sv, off);
        if (lane == 0 && sv) atomicAdd(&ghist[(b * NREP + rep) * GSTRIDE], sv);
    }
}

__global__ void __launch_bounds__(64) k_final(const unsigned int* __restrict__ ghist,
                                              float* __restrict__ out) {
    int t = threadIdx.x;
    if (t < NBINS) {
        unsigned int tot = 0;
        #pragma unroll
        for (int r = 0; r < NREP; ++r)
            tot += ghist[(t * NREP + r) * GSTRIDE];    // dispatch boundary = acquire
        out[6 + t] = (float)tot;
    }
}

extern "C" void kernel_launch(void* const* d_in, const int* in_sizes, int n_in,
                              void* d_out, int out_size, void* d_ws, size_t ws_size,
                              hipStream_t stream) {
    const float* x = (const float*)d_in[0];
    long long n = (long long)in_sizes[0];
    char* ws = (char*)d_ws;
    Partial* part = (Partial*)ws;
    unsigned int* ghist = (unsigned int*)(ws + OFF_G);
    uint2* mm = (uint2*)(ws + OFF_MM);
    float* out = (float*)d_out;

    k_reduce<<<dim3(NB1), dim3(256), 0, stream>>>(x, n, part, ghist, mm);
    k_hist<<<dim3(NB2), dim3(256), 0, stream>>>(x, n, part, ghist, mm, out);
    k_final<<<dim3(1), dim3(64), 0, stream>>>(ghist, out);
}